// Round 15
// baseline (178.668 us; speedup 1.0000x reference)
//
#include <hip/hip_runtime.h>

#define NT 64
#define NB 8192
#define NS 32
#define NF 16
#define DT 0.05f

typedef float f32x4 __attribute__((ext_vector_type(4)));
typedef short s16x8 __attribute__((ext_vector_type(8)));

// trunc-split f32 -> bf16 hi + bf16 lo (y ~= hi + lo, rel err ~2^-17)
__device__ __forceinline__ void bsplit(float v, unsigned short& hi, unsigned short& lo) {
    unsigned int u = __float_as_uint(v);
    hi = (unsigned short)(u >> 16);
    float rest = v - __uint_as_float(u & 0xFFFF0000u);
    lo = (unsigned short)(__float_as_uint(rest) >> 16);
}

__device__ __forceinline__ void split8(const float* p, s16x8& hi, s16x8& lo) {
#pragma unroll
    for (int e = 0; e < 8; ++e) {
        unsigned short hs, ls;
        bsplit(p[e], hs, ls);
        hi[e] = (short)hs;
        lo[e] = (short)ls;
    }
}

// tanh(x) = 1 - 2/(1 + exp2(K x)), K = 2*log2(e).
__device__ __forceinline__ float tanh1(float x) {
    const float K = 2.8853900817779268f;
    float e = __builtin_amdgcn_exp2f(K * x);
    float r = __builtin_amdgcn_rcpf(e + 1.0f);
    return fmaf(-2.0f, r, 1.0f);
}

// R13 post-mortem: MFMA structure validated (65us, absmax 0.0156) but
// OccupancyPercent=4.9%: 8192/16 = 512 waves on 1024 SIMDs = 0.5 waves/SIMD
// — half the GPU idle, zero latency cover for the ~1240cyc/iterate stall
// chain. MfmaUtil=5.3% -> the matrix pipe has ~20x headroom, so TRADE
// REDUNDANT MFMA FOR TLP: each wave owns only 4 REAL batches; tile cols are
// 4x-duplicated (gb = blk*4 + (m&3)), duplicate lanes compute identical
// values on real data, stores guarded to m<4. Waves x4 = 2048 = 2/SIMD,
// every SIMD occupied. Issue floor ~28us, path floor ~34us (8x redundancy
// at 4 waves/SIMD would be VALU-issue-bound ~57us — 4x is the optimum).
// Loop body / LDS layout / numerics byte-identical to R13.
// (R14 was an infra failure — this is the identical kernel resubmitted.)
__global__ __launch_bounds__(64) void rnes_kernel(
    const float* __restrict__ y0,
    const float* __restrict__ forces,
    const float* __restrict__ W,
    const float* __restrict__ U,
    const float* __restrict__ bias,
    float* __restrict__ out)
{
    const int lane = threadIdx.x;     // block = 1 wave
    const int m    = lane & 15;       // A-row o / B-col / D-col (tile col)
    const int h    = lane >> 4;       // k-quad: this lane holds k = 8h..8h+7
    const int gb   = blockIdx.x * 4 + (m & 3);   // 4 real batches, cols x4 dup

    // y staged as bf16 hi/lo: [16 cols][40 u16] (80B rows: b128-aligned,
    // bank spread <=2-way on both b64 writes and b128 reads).
    __shared__ __align__(16) unsigned short Yhi[16 * 40];
    __shared__ __align__(16) unsigned short Ylo[16 * 40];

    // A-fragments of W (constant): A[o][k=8h+e]; block0 o=m, block1 o=m+16.
    s16x8 WA0h, WA0l, WA1h, WA1l;
    split8(W + m * NS + 8 * h,        WA0h, WA0l);
    split8(W + (m + 16) * NS + 8 * h, WA1h, WA1l);

    // A-fragments of U, K padded 16->32 (k>=16 i.e. h>=2 lanes: zeros).
    s16x8 UA0h = {0,0,0,0,0,0,0,0}, UA0l = UA0h, UA1h = UA0h, UA1l = UA0h;
    if (h < 2) {
        split8(U + m * NF + 8 * h,        UA0h, UA0l);
        split8(U + (m + 16) * NF + 8 * h, UA1h, UA1l);
    }

    // bias in D layout: lane holds states 4h+r (A) and 16+4h+r (B).
    const f32x4 biasA = *(const f32x4*)(bias + 4 * h);
    const f32x4 biasB = *(const f32x4*)(bias + 16 + 4 * h);

    // y_prev in D layout; out[0] = y0 (only the 4 real cols store).
    const float* yb = y0 + (size_t)gb * NS;
    f32x4 ypA = *(const f32x4*)(yb + 4 * h);
    f32x4 ypB = *(const f32x4*)(yb + 16 + 4 * h);
    if (m < 4) {
        float* o0 = out + (size_t)gb * NS;
        __builtin_nontemporal_store(ypA, (f32x4*)(o0 + 4 * h));
        __builtin_nontemporal_store(ypB, (f32x4*)(o0 + 16 + 4 * h));
    }
    f32x4 yppA = ypA, yppB = ypB;

    // forces: B-operand of fu. Lane needs u[batch gb][f=8h+e], h<2 only.
    const size_t fstep = (size_t)NB * NF;
    const float* fba = forces + (size_t)gb * NF + 8 * h;
    f32x4 un0 = {0.f,0.f,0.f,0.f}, un1 = un0;
    if (h < 2) {
        un0 = __builtin_nontemporal_load((const f32x4*)(fba + fstep));
        un1 = __builtin_nontemporal_load((const f32x4*)(fba + fstep + 4));
    }

    for (int k = 1; k < NT; ++k) {
        // u B-fragments (bf16 hi/lo; zeros for h>=2 = padded K rows).
        s16x8 Buh = {0,0,0,0,0,0,0,0}, Bul = Buh;
        if (h < 2) {
            float uv[8] = {un0[0],un0[1],un0[2],un0[3],un1[0],un1[1],un1[2],un1[3]};
            split8(uv, Buh, Bul);
        }
        // fu = bias + U u  (3-term hi/lo split, 2 o-blocks, f32 accumulate)
        f32x4 fuA = biasA;
        fuA = __builtin_amdgcn_mfma_f32_16x16x32_bf16(UA0l, Buh, fuA, 0, 0, 0);
        fuA = __builtin_amdgcn_mfma_f32_16x16x32_bf16(UA0h, Bul, fuA, 0, 0, 0);
        fuA = __builtin_amdgcn_mfma_f32_16x16x32_bf16(UA0h, Buh, fuA, 0, 0, 0);
        f32x4 fuB = biasB;
        fuB = __builtin_amdgcn_mfma_f32_16x16x32_bf16(UA1l, Buh, fuB, 0, 0, 0);
        fuB = __builtin_amdgcn_mfma_f32_16x16x32_bf16(UA1h, Bul, fuB, 0, 0, 0);
        fuB = __builtin_amdgcn_mfma_f32_16x16x32_bf16(UA1h, Buh, fuB, 0, 0, 0);

        // prefetch next step's forces
        if (h < 2) {
            int kn = (k + 1 < NT) ? (k + 1) : (NT - 1);
            un0 = __builtin_nontemporal_load((const f32x4*)(fba + (size_t)kn * fstep));
            un1 = __builtin_nontemporal_load((const f32x4*)(fba + (size_t)kn * fstep + 4));
        }

        // predictor: linear extrapolation (R10-validated).
        f32x4 yA = ypA + (ypA - yppA);
        f32x4 yB = ypB + (ypB - yppB);

        // corrector: y <- yp + DT*tanh(W y + fu)
        auto iterate = [&]() {
            // split y -> bf16 hi/lo, write D-layout rows into LDS
            unsigned dh0, dh1, dl0, dl1;
            {
                unsigned short h0,h1,h2,h3,l0,l1,l2,l3;
                bsplit(yA[0],h0,l0); bsplit(yA[1],h1,l1);
                bsplit(yA[2],h2,l2); bsplit(yA[3],h3,l3);
                dh0 = (unsigned)h0 | ((unsigned)h1 << 16);
                dh1 = (unsigned)h2 | ((unsigned)h3 << 16);
                dl0 = (unsigned)l0 | ((unsigned)l1 << 16);
                dl1 = (unsigned)l2 | ((unsigned)l3 << 16);
            }
            *reinterpret_cast<unsigned long long*>(&Yhi[m * 40 + 4 * h]) =
                (unsigned long long)dh0 | ((unsigned long long)dh1 << 32);
            *reinterpret_cast<unsigned long long*>(&Ylo[m * 40 + 4 * h]) =
                (unsigned long long)dl0 | ((unsigned long long)dl1 << 32);
            {
                unsigned short h0,h1,h2,h3,l0,l1,l2,l3;
                bsplit(yB[0],h0,l0); bsplit(yB[1],h1,l1);
                bsplit(yB[2],h2,l2); bsplit(yB[3],h3,l3);
                dh0 = (unsigned)h0 | ((unsigned)h1 << 16);
                dh1 = (unsigned)h2 | ((unsigned)h3 << 16);
                dl0 = (unsigned)l0 | ((unsigned)l1 << 16);
                dl1 = (unsigned)l2 | ((unsigned)l3 << 16);
            }
            *reinterpret_cast<unsigned long long*>(&Yhi[m * 40 + 16 + 4 * h]) =
                (unsigned long long)dh0 | ((unsigned long long)dh1 << 32);
            *reinterpret_cast<unsigned long long*>(&Ylo[m * 40 + 16 + 4 * h]) =
                (unsigned long long)dl0 | ((unsigned long long)dl1 << 32);
            asm volatile("" ::: "memory");   // single-wave block: DS in-order

            // read B fragments: lane reads col m, states 8h..8h+7 (b128)
            s16x8 Bh = *reinterpret_cast<const s16x8*>(&Yhi[m * 40 + 8 * h]);
            s16x8 Bl = *reinterpret_cast<const s16x8*>(&Ylo[m * 40 + 8 * h]);

            // z = W y + fu  (3-term hi/lo, 2 independent o-block chains)
            f32x4 zA = fuA;
            zA = __builtin_amdgcn_mfma_f32_16x16x32_bf16(WA0l, Bh, zA, 0, 0, 0);
            zA = __builtin_amdgcn_mfma_f32_16x16x32_bf16(WA0h, Bl, zA, 0, 0, 0);
            zA = __builtin_amdgcn_mfma_f32_16x16x32_bf16(WA0h, Bh, zA, 0, 0, 0);
            f32x4 zB = fuB;
            zB = __builtin_amdgcn_mfma_f32_16x16x32_bf16(WA1l, Bh, zB, 0, 0, 0);
            zB = __builtin_amdgcn_mfma_f32_16x16x32_bf16(WA1h, Bl, zB, 0, 0, 0);
            zB = __builtin_amdgcn_mfma_f32_16x16x32_bf16(WA1h, Bh, zB, 0, 0, 0);

#pragma unroll
            for (int r = 0; r < 4; ++r) {
                yA[r] = fmaf(DT, tanh1(zA[r]), ypA[r]);
                yB[r] = fmaf(DT, tanh1(zB[r]), ypB[r]);
            }
        };
        iterate();
        iterate();
        if (k == 1) iterate();   // no extrapolation history at k=1

        yppA = ypA; yppB = ypB;
        ypA = yA;   ypB = yB;

        if (m < 4) {
            float* op = out + ((size_t)k * NB + gb) * NS;
            __builtin_nontemporal_store(yA, (f32x4*)(op + 4 * h));
            __builtin_nontemporal_store(yB, (f32x4*)(op + 16 + 4 * h));
        }
    }
}

extern "C" void kernel_launch(void* const* d_in, const int* in_sizes, int n_in,
                              void* d_out, int out_size, void* d_ws, size_t ws_size,
                              hipStream_t stream) {
    const float* y0     = (const float*)d_in[0];
    const float* forces = (const float*)d_in[1];
    const float* W      = (const float*)d_in[2];
    const float* U      = (const float*)d_in[3];
    const float* b      = (const float*)d_in[4];
    float* out = (float*)d_out;

    dim3 grid(NB / 4);    // 2048 blocks x 1 wave x 4 real batches = 8192
    dim3 block(64);
    rnes_kernel<<<grid, block, 0, stream>>>(y0, forces, W, U, b, out);
}

// Round 16
// 142.554 us; speedup vs baseline: 1.2533x; 1.2533x over previous
//
#include <hip/hip_runtime.h>

#define NT 64
#define NB 8192
#define NS 32
#define NF 16
#define DT 0.05f

typedef float f32x4 __attribute__((ext_vector_type(4)));
typedef short s16x8 __attribute__((ext_vector_type(8)));

// trunc-split f32 -> bf16 hi + bf16 lo (v ~= hi + lo, rel err ~2^-17)
__device__ __forceinline__ void bsplit(float v, unsigned short& hi, unsigned short& lo) {
    unsigned int u = __float_as_uint(v);
    hi = (unsigned short)(u >> 16);
    float rest = v - __uint_as_float(u & 0xFFFF0000u);
    lo = (unsigned short)(__float_as_uint(rest) >> 16);
}

__device__ __forceinline__ void split8(const float* p, s16x8& hi, s16x8& lo) {
#pragma unroll
    for (int e = 0; e < 8; ++e) {
        unsigned short hs, ls;
        bsplit(p[e], hs, ls);
        hi[e] = (short)hs;
        lo[e] = (short)ls;
    }
}

// tanh(x) = 1 - 2/(1 + exp2(K x)), K = 2*log2(e).
__device__ __forceinline__ float tanh1(float x) {
    const float K = 2.8853900817779268f;
    float e = __builtin_amdgcn_exp2f(K * x);
    float r = __builtin_amdgcn_rcpf(e + 1.0f);
    return fmaf(-2.0f, r, 1.0f);
}

// R15 post-mortem: wall = serial-chain latency x 126 iterates (TLP can't
// shorten it; duplication saturated VALU at 59% and HURT). VALU issue ~500
// cyc/iterate vs ~250 source -> allocator remat/spill (VGPR=52 vs ~74 live;
// launch_bounds(64) default targets 8 waves/EU = 64 regs we can't use).
//
// R16: split the two o-blocks across 2 WAVES in one block. Wave w computes
// states 16w..16w+15 only: per-lane tanh/pack HALVES (4 not 8), MFMA chain
// halves (3 not 6), live set ~55-65 regs fits the allocator naturally;
// launch_bounds(128,1) = min-1-wave/EU -> 512-reg budget, no occupancy
// chase. y-exchange between waves: double-buffered LDS plane + ONE
// __syncthreads per iterate (double-buffer + intervening barrier covers
// WAR; waves write disjoint state ranges). 1024 waves = 1/SIMD of REAL
// work. All MFMA mappings identical to validated R13 (A row = W[16w+m],
// B = y states 8h..8h+7 of batch m, D rows 4h+r -> states 16w+4h+r);
// 3-term hi/lo chain in the same order -> bit-identical numerics.
__global__ __launch_bounds__(128, 1) void rnes_kernel(
    const float* __restrict__ y0,
    const float* __restrict__ forces,
    const float* __restrict__ W,
    const float* __restrict__ U,
    const float* __restrict__ bias,
    float* __restrict__ out)
{
    const int tid  = threadIdx.x;
    const int w    = tid >> 6;        // o-block: states 16w..16w+15
    const int lane = tid & 63;
    const int m    = lane & 15;       // batch within tile / B,D col
    const int h    = lane >> 4;       // k-quad: holds k = 8h..8h+7
    const int gb   = blockIdx.x * 16 + m;   // global batch
    const int so   = 16 * w + 4 * h;  // first output state of this lane

    // y staged bf16 hi/lo, DOUBLE-BUFFERED: [buf][batch][state], rows padded
    // to 40 u16 (80 B: b128-aligned reads, low-conflict strides — R13 layout).
    __shared__ __align__(16) unsigned short Yhi[2][16][40];
    __shared__ __align__(16) unsigned short Ylo[2][16][40];

    // A-fragment of W for this wave's o-block: A[i=m][k=8h+e] = W[16w+m][k].
    s16x8 Wh, Wl;
    split8(W + (16 * w + m) * NS + 8 * h, Wh, Wl);

    // A-fragment of U (K padded 16->32: h>=2 lanes zero).
    s16x8 Uh = {0,0,0,0,0,0,0,0}, Ul = Uh;
    if (h < 2) split8(U + (16 * w + m) * NF + 8 * h, Uh, Ul);

    // bias / y_prev in D layout (states so..so+3 of batch gb); out[0] = y0.
    const f32x4 bv = *(const f32x4*)(bias + so);
    f32x4 yp = *(const f32x4*)(y0 + (size_t)gb * NS + so);
    __builtin_nontemporal_store(yp, (f32x4*)(out + (size_t)gb * NS + so));
    f32x4 ypp = yp;   // predictor history (k=1: extrapolation collapses)

    // forces prefetch: u[gb][8h..8h+7], h<2 only (B-operand of fu).
    const size_t fstep = (size_t)NB * NF;
    const float* fba = forces + (size_t)gb * NF + 8 * h;
    f32x4 un0 = {0.f,0.f,0.f,0.f}, un1 = un0;
    if (h < 2) {
        un0 = __builtin_nontemporal_load((const f32x4*)(fba + fstep));
        un1 = __builtin_nontemporal_load((const f32x4*)(fba + fstep + 4));
    }

    int buf = 0;
    for (int k = 1; k < NT; ++k) {
        // u B-fragments (bf16 hi/lo; zeros h>=2 = padded K rows).
        s16x8 Buh = {0,0,0,0,0,0,0,0}, Bul = Buh;
        if (h < 2) {
            float uv[8] = {un0[0],un0[1],un0[2],un0[3],un1[0],un1[1],un1[2],un1[3]};
            split8(uv, Buh, Bul);
        }
        // fu = bias + U u (3-term hi/lo chain, this wave's o-block only)
        f32x4 fu = bv;
        fu = __builtin_amdgcn_mfma_f32_16x16x32_bf16(Ul, Buh, fu, 0, 0, 0);
        fu = __builtin_amdgcn_mfma_f32_16x16x32_bf16(Uh, Bul, fu, 0, 0, 0);
        fu = __builtin_amdgcn_mfma_f32_16x16x32_bf16(Uh, Buh, fu, 0, 0, 0);

        // prefetch next step's forces
        if (h < 2) {
            int kn = (k + 1 < NT) ? (k + 1) : (NT - 1);
            un0 = __builtin_nontemporal_load((const f32x4*)(fba + (size_t)kn * fstep));
            un1 = __builtin_nontemporal_load((const f32x4*)(fba + (size_t)kn * fstep + 4));
        }

        // predictor: linear extrapolation (R10-validated).
        f32x4 y = yp + (yp - ypp);

        // corrector: y <- yp + DT*tanh(W y + fu)
        auto iterate = [&]() {
            // pack this lane's 4 states -> LDS [buf][m][so..so+3] (hi & lo)
            unsigned short h0,h1,h2,h3,l0,l1,l2,l3;
            bsplit(y[0],h0,l0); bsplit(y[1],h1,l1);
            bsplit(y[2],h2,l2); bsplit(y[3],h3,l3);
            unsigned long long hw =
                (unsigned long long)((unsigned)h0 | ((unsigned)h1 << 16)) |
                ((unsigned long long)((unsigned)h2 | ((unsigned)h3 << 16)) << 32);
            unsigned long long lw =
                (unsigned long long)((unsigned)l0 | ((unsigned)l1 << 16)) |
                ((unsigned long long)((unsigned)l2 | ((unsigned)l3 << 16)) << 32);
            *reinterpret_cast<unsigned long long*>(&Yhi[buf][m][so]) = hw;
            *reinterpret_cast<unsigned long long*>(&Ylo[buf][m][so]) = lw;
            __syncthreads();   // both waves' halves visible

            // B fragments: full y (states 8h..8h+7) of batch m
            s16x8 Bh = *reinterpret_cast<const s16x8*>(&Yhi[buf][m][8 * h]);
            s16x8 Bl = *reinterpret_cast<const s16x8*>(&Ylo[buf][m][8 * h]);
            buf ^= 1;          // next iterate writes the other plane

            // z = W y + fu (3-term chain, order identical to R13)
            f32x4 z = fu;
            z = __builtin_amdgcn_mfma_f32_16x16x32_bf16(Wl, Bh, z, 0, 0, 0);
            z = __builtin_amdgcn_mfma_f32_16x16x32_bf16(Wh, Bl, z, 0, 0, 0);
            z = __builtin_amdgcn_mfma_f32_16x16x32_bf16(Wh, Bh, z, 0, 0, 0);

#pragma unroll
            for (int r = 0; r < 4; ++r)
                y[r] = fmaf(DT, tanh1(z[r]), yp[r]);
        };
        iterate();
        iterate();
        if (k == 1) iterate();   // k is block-uniform: barrier-safe

        ypp = yp;
        yp  = y;
        __builtin_nontemporal_store(y, (f32x4*)(out + ((size_t)k * NB + gb) * NS + so));
    }
}

extern "C" void kernel_launch(void* const* d_in, const int* in_sizes, int n_in,
                              void* d_out, int out_size, void* d_ws, size_t ws_size,
                              hipStream_t stream) {
    const float* y0     = (const float*)d_in[0];
    const float* forces = (const float*)d_in[1];
    const float* W      = (const float*)d_in[2];
    const float* U      = (const float*)d_in[3];
    const float* b      = (const float*)d_in[4];
    float* out = (float*)d_out;

    dim3 grid(NB / 16);   // 512 blocks x 2 waves (o-block split) x 16 batches
    dim3 block(128);
    rnes_kernel<<<grid, block, 0, stream>>>(y0, forces, W, U, b, out);
}